// Round 3
// baseline (2451.944 us; speedup 1.0000x reference)
//
#include <hip/hip_runtime.h>
#include <cstdint>

#define T_STEPS 128
#define BATCH   1024
#define D_INPUT 96
#define H_DIM   128
#define NWIN    163   // 121 full 7-frame windows + 6 prefix partials + 36 clipped partials

// window table: widx -> (start frame, length)
__device__ __forceinline__ void win_decode(int widx, int& start, int& len) {
    if (widx < 121)      { start = widx;        len = 7; }            // [w, w+6]
    else if (widx < 127) { start = 0;           len = widx - 120; }   // s=0 grow, len 1..6
    else { const int r = widx - 127; const int s = 1 + r / 6;
           len = 1 + r % 6;          start = 7 * s - 1; }             // s>=1 grow partials
}

// (t, s) -> widx, or -1 when the reference window is empty (cur1 == +0)
__device__ __forceinline__ int widx_for(int t, int s) {
    if (t >= 49) return t - 49 + 7 * s;                 // slide regime: full windows
    if (s == 0)  return 121 + min(5, t);                // [0, min(5,t)]
    const int st = 7 * s - 1;
    if (t < st) return -1;
    const int len = min(7, t - st + 1);
    return (len == 7) ? st : (127 + (s - 1) * 6 + (len - 1));
}

// ---------------------------------------------------------------------------
// kA: CUR1[widx][b][h] = seqFMA_{d=0..95}( wsum[d], Win[h][d] ), where
// wsum[d] = ascending fp32 sum of x[k][b][d] over the window's frames —
// bit-matching numpy's axis-reduce followed by BLAS sgemm (single-accumulator,
// ascending-k FMA, beta=0).
// ---------------------------------------------------------------------------
__global__ __launch_bounds__(256) void kA_wincur(const float* __restrict__ x,
                                                 const float* __restrict__ Win,
                                                 float* __restrict__ CUR1) {
    const int widx = blockIdx.x;
    const int b = blockIdx.y * 256 + threadIdx.x;
    int start, len; win_decode(widx, start, len);

    const float* xp = x + ((size_t)start * BATCH + b) * D_INPUT;
    float xs[D_INPUT];
#pragma unroll
    for (int d = 0; d < D_INPUT; d += 4) {
        const float4 v = *(const float4*)(xp + d);
        xs[d] = v.x; xs[d+1] = v.y; xs[d+2] = v.z; xs[d+3] = v.w;
    }
    for (int k = 1; k < len; ++k) {                     // ascending frame order
        const float* xk = xp + (size_t)k * BATCH * D_INPUT;
#pragma unroll
        for (int d = 0; d < D_INPUT; d += 4) {
            const float4 v = *(const float4*)(xk + d);
            xs[d]   = __fadd_rn(xs[d],   v.x);
            xs[d+1] = __fadd_rn(xs[d+1], v.y);
            xs[d+2] = __fadd_rn(xs[d+2], v.z);
            xs[d+3] = __fadd_rn(xs[d+3], v.w);
        }
    }

    float* op = CUR1 + ((size_t)widx * BATCH + b) * H_DIM;
    for (int h = 0; h < H_DIM; h += 2) {
        const float* w0 = Win + (size_t)h * D_INPUT;    // wave-uniform -> s_loads
        const float* w1 = w0 + D_INPUT;
        float a0 = 0.f, a1 = 0.f;
#pragma unroll
        for (int d = 0; d < D_INPUT; ++d) {             // ascending d, one accumulator
            a0 = __fmaf_rn(xs[d], w0[d], a0);
            a1 = __fmaf_rn(xs[d], w1[d], a1);
        }
        float2 o; o.x = a0; o.y = a1;
        *(float2*)(op + h) = o;
    }
}

// ---------------------------------------------------------------------------
// kB: per (t,b): 7 SNN steps in bit-exact np-fp32 order. One wave per pair,
// 4 pairs serial per wave. Lane l owns neurons i0=2l, i0+1. W_h0 in LDS
// (XOR-swizzled so the (i0,i0+1) float2 stays adjacent/8B-aligned). Spike
// accumulations walk set bits of the ballot masks in ASCENDING h order with
// __fadd_rn (== sgemm's conditional fmaf chain for 0/1 inputs). W_out via
// __shfl from registers (uniform lane index -> readlane). mem_out recurrence
// kept literal: mem = rn(rn(0.9*mem) + cur).
// ---------------------------------------------------------------------------
__device__ __forceinline__ int lw_idx(int h, int i) {
    return (h << 7) | (i ^ ((h & 63) << 1));
}

__global__ __launch_bounds__(256) void kB_snn(const float* __restrict__ CUR1,
                                              const float* __restrict__ Wh0,
                                              const float* __restrict__ Wout,
                                              const float* __restrict__ vxp,
                                              const float* __restrict__ vyp,
                                              float* __restrict__ out) {
    __shared__ float lw[H_DIM * H_DIM];   // exactly 64 KB
    const int tid = threadIdx.x;
    for (int e = tid; e < H_DIM * H_DIM; e += 256) {
        const int i = e >> 7, h = e & 127;              // Wh0 flat = i*128 + h
        lw[lw_idx(h, i)] = Wh0[e];
    }
    __syncthreads();

    const int wave = tid >> 6, lane = tid & 63;
    const int t  = blockIdx.y;
    const int i0 = lane << 1;
    // W_out columns for this lane's two neurons (for the __shfl broadcast)
    const float wex = Wout[i0],         wey = Wout[H_DIM + i0];       // h = 2*lane
    const float wox = Wout[i0 + 1],     woy = Wout[H_DIM + i0 + 1];   // h = 2*lane+1
    const float vx = vxp[0], vy = vyp[0];

    for (int k = 0; k < 4; ++k) {
        const int b = (blockIdx.x << 4) + (wave << 2) + k;

        // ---- cur1 for the 7 sub-steps ------------------------------------
        float c1a[7], c1b[7];
#pragma unroll
        for (int s = 0; s < 7; ++s) {
            const int wi = widx_for(t, s);              // wave-uniform
            if (wi >= 0) {
                const float2 v = *(const float2*)
                    &CUR1[((size_t)wi * BATCH + b) * H_DIM + i0];
                c1a[s] = v.x; c1b[s] = v.y;
            } else { c1a[s] = 0.f; c1b[s] = 0.f; }
        }

        // ---- 7 SNN steps --------------------------------------------------
        float m1a = 0.f, m1b = 0.f, m2a = 0.f, m2b = 0.f;
        float oa = 0.f, ob = 0.f;                       // mem_out (wave-uniform)
        bool s1a = false, s1b = false, s2a = false, s2b = false;
#pragma unroll
        for (int s = 0; s < 7; ++s) {
            // mem1 = rn(rn(0.9*mem1) + cur) * (1-reset); reset = prev spike
            m1a = s1a ? 0.f : __fadd_rn(__fmul_rn(0.9f, m1a), c1a[s]);
            m1b = s1b ? 0.f : __fadd_rn(__fmul_rn(0.9f, m1b), c1b[s]);
            s1a = m1a > 0.5f; s1b = m1b > 0.5f;

            // cur2[i] = ascending-h conditional rn-adds of W_h0[i][h]
            uint64_t me = __ballot(s1a);                // bit l -> h = 2l
            uint64_t mo = __ballot(s1b);                // bit l -> h = 2l+1
            float c2a = 0.f, c2b = 0.f;
            while (me | mo) {
                const unsigned le  = me ? (unsigned)__builtin_ctzll(me) : 64u;
                const unsigned lo2 = mo ? (unsigned)__builtin_ctzll(mo) : 64u;
                int h;
                if (le <= lo2) { h = (int)(le << 1);        me &= me - 1; }
                else           { h = (int)((lo2 << 1) | 1); mo &= mo - 1; }
                const float2 w = *(const float2*)&lw[lw_idx(h, i0)];
                c2a = __fadd_rn(c2a, w.x); c2b = __fadd_rn(c2b, w.y);
            }

            m2a = s2a ? 0.f : __fadd_rn(__fmul_rn(0.9f, m2a), c2a);
            m2b = s2b ? 0.f : __fadd_rn(__fmul_rn(0.9f, m2b), c2b);
            s2a = m2a > 0.5f; s2b = m2b > 0.5f;

            // cur_out[o] = ascending-h conditional rn-adds of W_out[o][h]
            uint64_t pe = __ballot(s2a);
            uint64_t po = __ballot(s2b);
            float co0 = 0.f, co1 = 0.f;
            while (pe | po) {
                const unsigned le  = pe ? (unsigned)__builtin_ctzll(pe) : 64u;
                const unsigned lo2 = po ? (unsigned)__builtin_ctzll(po) : 64u;
                float wx, wy;
                if (le <= lo2) { pe &= pe - 1;
                    wx = __shfl(wex, (int)le);  wy = __shfl(wey, (int)le); }
                else           { po &= po - 1;
                    wx = __shfl(wox, (int)lo2); wy = __shfl(woy, (int)lo2); }
                co0 = __fadd_rn(co0, wx); co1 = __fadd_rn(co1, wy);
            }

            // mem_out = rn(rn(0.9*mem_out) + cur_out)   (no reset)
            oa = __fadd_rn(__fmul_rn(0.9f, oa), co0);
            ob = __fadd_rn(__fmul_rn(0.9f, ob), co1);
        }

        // ---- write: pred * vxy -------------------------------------------
        if (lane == 0) {
            float2 o;
            o.x = __fmul_rn(oa, vx);
            o.y = __fmul_rn(ob, vy);
            *(float2*)(out + ((size_t)t * BATCH + b) * 2) = o;
        }
    }
}

// ---------------------------------------------------------------------------
extern "C" void kernel_launch(void* const* d_in, const int* in_sizes, int n_in,
                              void* d_out, int out_size, void* d_ws, size_t ws_size,
                              hipStream_t stream) {
    const float* x    = (const float*)d_in[0];   // (128,1024,96)
    const float* Win  = (const float*)d_in[1];   // (128,96)
    const float* Wh0  = (const float*)d_in[2];   // (128,128)
    const float* Wout = (const float*)d_in[3];   // (2,128)
    const float* vx   = (const float*)d_in[4];   // (1,)
    const float* vy   = (const float*)d_in[5];   // (1,)
    float* out  = (float*)d_out;                 // (128,1024,2)
    float* CUR1 = (float*)d_ws;                  // 163*1024*128*4 = 85.5 MB

    kA_wincur<<<dim3(NWIN, BATCH / 256), dim3(256), 0, stream>>>(x, Win, CUR1);
    kB_snn   <<<dim3(BATCH / 16, T_STEPS), dim3(256), 0, stream>>>(CUR1, Wh0, Wout, vx, vy, out);
}